// Round 1
// baseline (781.760 us; speedup 1.0000x reference)
//
#include <hip/hip_runtime.h>
#include <hip/hip_bf16.h>
#include <math.h>

// Problem constants
#define NB    2048          // B
#define ACT   14
#define NC    128           // C
#define NH    32            // H
#define NNODE (NB*ACT)      // 28672
#define NEDGE (NB*ACT*ACT)  // 401408
#define NPAIR (NB*ACT*ACT)  // 401408 output rows (b, 196)

// ---------------------------------------------------------------------------
// K1/K5: tiled fp32 GEMM, A [nrows x 128] @ W [128 x ncols] -> C [nrows x ncols]
// 64x64 tile, 256 threads, 4x4 register blocking, XOR-swizzled A tile in LDS.
// ---------------------------------------------------------------------------
__global__ __launch_bounds__(256) void gemm_k128(
    const float* __restrict__ A, const float* __restrict__ W,
    float* __restrict__ C, int ncols)
{
    __shared__ float As[64 * 128];   // 32 KB
    __shared__ float Ws[128 * 64];   // 32 KB
    const int tid  = threadIdx.x;
    const int row0 = blockIdx.x * 64;
    const int col0 = blockIdx.y * 64;

    // stage A tile (64 rows x 128 K), swizzled: col ^= ((row>>2)&3)<<2
    {
        const float4* Ag = (const float4*)(A + (size_t)row0 * 128);
#pragma unroll
        for (int it = 0; it < 8; ++it) {
            int idx = tid + it * 256;          // float4 index in tile
            int r = idx >> 5;
            int c = (idx & 31) << 2;           // float col, multiple of 4
            int cs = c ^ (((r >> 2) & 3) << 2);
            *((float4*)&As[r * 128 + cs]) = Ag[r * 32 + (c >> 2)];
        }
        // stage W tile (128 K x 64 cols)
#pragma unroll
        for (int it = 0; it < 8; ++it) {
            int idx = tid + it * 256;
            int k = idx >> 4;
            int c = (idx & 15) << 2;
            *((float4*)&Ws[k * 64 + c]) =
                *((const float4*)&W[(size_t)k * ncols + col0 + c]);
        }
    }
    __syncthreads();

    const int tx = tid & 15;       // col group
    const int ty = tid >> 4;       // row group
    const int ri0 = ty * 4;

    float acc[4][4] = {};
    for (int k = 0; k < 128; k += 4) {
        float a_s[4][4];
        float w_s[4][4];
#pragma unroll
        for (int i = 0; i < 4; ++i) {
            int r = ri0 + i;
            *((float4*)&a_s[i][0]) =
                *((const float4*)&As[r * 128 + (k ^ (((r >> 2) & 3) << 2))]);
        }
#pragma unroll
        for (int kk = 0; kk < 4; ++kk) {
            *((float4*)&w_s[kk][0]) =
                *((const float4*)&Ws[(k + kk) * 64 + tx * 4]);
        }
#pragma unroll
        for (int kk = 0; kk < 4; ++kk)
#pragma unroll
            for (int i = 0; i < 4; ++i)
#pragma unroll
                for (int j = 0; j < 4; ++j)
                    acc[i][j] += a_s[i][kk] * w_s[kk][j];
    }

#pragma unroll
    for (int i = 0; i < 4; ++i) {
        float4 v = make_float4(acc[i][0], acc[i][1], acc[i][2], acc[i][3]);
        *((float4*)&C[(size_t)(row0 + ri0 + i) * ncols + col0 + tx * 4]) = v;
    }
}

// ---------------------------------------------------------------------------
// pack W1 [256x32] -> Wp [128x64]  (cols 0..31 = W1[k], cols 32..63 = W1[128+k])
// ---------------------------------------------------------------------------
__global__ void pack_w1(const float* __restrict__ W1, float* __restrict__ Wp)
{
    int idx = blockIdx.x * blockDim.x + threadIdx.x;   // 0..8191
    if (idx >= 128 * 64) return;
    int k = idx >> 6, c = idx & 63;
    Wp[idx] = (c < 32) ? W1[k * 32 + c] : W1[(128 + k) * 32 + (c - 32)];
}

// ---------------------------------------------------------------------------
// degree count (int atomics) and dinv
// ---------------------------------------------------------------------------
__global__ void deg_count(const int* __restrict__ dst, int* __restrict__ deg)
{
    int e = blockIdx.x * blockDim.x + threadIdx.x;
    if (e < NEDGE) atomicAdd(&deg[dst[e]], 1);
}

__global__ void make_dinv(const int* __restrict__ deg, float* __restrict__ dinv)
{
    int i = blockIdx.x * blockDim.x + threadIdx.x;
    if (i < NNODE) dinv[i] = rsqrtf((float)deg[i] + 1.0f);
}

// ---------------------------------------------------------------------------
// scatter: agg[dst] += xw[src] * dinv[src]*dinv[dst]   (fp32 atomics)
// one thread per (edge, 4-channel group); 32 threads cover 128 channels
// ---------------------------------------------------------------------------
__global__ __launch_bounds__(256) void scatter_edges(
    const int* __restrict__ src, const int* __restrict__ dst,
    const float* __restrict__ dinv, const float* __restrict__ xw,
    float* __restrict__ agg)
{
    int gid = blockIdx.x * blockDim.x + threadIdx.x;
    int e = gid >> 5;
    if (e >= NEDGE) return;
    int q = gid & 31;
    int s = src[e], d = dst[e];
    float norm = dinv[s] * dinv[d];
    float4 xv = ((const float4*)(xw + (size_t)s * NC))[q];
    float* ap = agg + (size_t)d * NC + q * 4;
    atomicAdd(ap + 0, xv.x * norm);
    atomicAdd(ap + 1, xv.y * norm);
    atomicAdd(ap + 2, xv.z * norm);
    atomicAdd(ap + 3, xv.w * norm);
}

// ---------------------------------------------------------------------------
// x = relu(agg + xw*dinv^2 + bias) + state    (written in-place into xw)
// ---------------------------------------------------------------------------
__global__ __launch_bounds__(256) void build_x(
    float* __restrict__ xw, const float* __restrict__ agg,
    const float* __restrict__ dinv, const float* __restrict__ bias,
    const float* __restrict__ state)
{
    int idx = blockIdx.x * blockDim.x + threadIdx.x;   // float4 index
    if (idx >= NNODE * 32) return;
    int row = idx >> 5;
    int c4 = idx & 31;
    float dv = dinv[row];
    float d2 = dv * dv;
    float4 xv = ((const float4*)xw)[idx];
    float4 ag = ((const float4*)agg)[idx];
    float4 bv = ((const float4*)bias)[c4];
    float4 st = ((const float4*)state)[idx];
    float4 r;
    r.x = fmaxf(ag.x + xv.x * d2 + bv.x, 0.f) + st.x;
    r.y = fmaxf(ag.y + xv.y * d2 + bv.y, 0.f) + st.y;
    r.z = fmaxf(ag.z + xv.z * d2 + bv.z, 0.f) + st.z;
    r.w = fmaxf(ag.w + xv.w * d2 + bv.w, 0.f) + st.w;
    ((float4*)xw)[idx] = r;
}

// ---------------------------------------------------------------------------
// pairs kernel: per (b, i, j): h1 = leaky(u[b,i]+v[b,j]+b1); h2 = leaky(h1@W2+b2);
// mu = softplus(h2@muW + mu_b + 1e-10); std = exp(clip(h2@sigW + sig_b, -20, 2))
// ---------------------------------------------------------------------------
__device__ __forceinline__ float softplusf(float z)
{
    return z > 0.f ? z + log1pf(expf(-z)) : log1pf(expf(z));
}

__global__ __launch_bounds__(256) void pairs_kernel(
    const float* __restrict__ uv, const float* __restrict__ W2,
    const float* __restrict__ b1, const float* __restrict__ b2,
    const float* __restrict__ muW, const float* __restrict__ mu_b,
    const float* __restrict__ sigW, const float* __restrict__ sig_b,
    float* __restrict__ out)
{
    __shared__ float W2s[1024];
    __shared__ float b1s[32], b2s[32], muWs[32], sigWs[32];
    const int tid = threadIdx.x;
    for (int i = tid; i < 1024; i += 256) W2s[i] = W2[i];
    if (tid < 32) {
        b1s[tid] = b1[tid];
        b2s[tid] = b2[tid];
        muWs[tid] = muW[tid];
        sigWs[tid] = sigW[tid];
    }
    __syncthreads();

    int gid = blockIdx.x * 256 + tid;          // 0 .. NPAIR-1
    int b = gid / 196;
    int p = gid - b * 196;
    int i = p / 14;
    int j = p - i * 14;

    const float* up = uv + (size_t)(b * ACT + i) * 64;
    const float* vp = uv + (size_t)(b * ACT + j) * 64 + 32;

    float h1[32];
#pragma unroll
    for (int k4 = 0; k4 < 8; ++k4) {
        float4 uu = ((const float4*)up)[k4];
        float4 vv = ((const float4*)vp)[k4];
        float z0 = uu.x + vv.x + b1s[k4 * 4 + 0];
        float z1 = uu.y + vv.y + b1s[k4 * 4 + 1];
        float z2 = uu.z + vv.z + b1s[k4 * 4 + 2];
        float z3 = uu.w + vv.w + b1s[k4 * 4 + 3];
        h1[k4 * 4 + 0] = z0 > 0.f ? z0 : 0.01f * z0;
        h1[k4 * 4 + 1] = z1 > 0.f ? z1 : 0.01f * z1;
        h1[k4 * 4 + 2] = z2 > 0.f ? z2 : 0.01f * z2;
        h1[k4 * 4 + 3] = z3 > 0.f ? z3 : 0.01f * z3;
    }

    float h2[32];
#pragma unroll
    for (int l = 0; l < 32; ++l) h2[l] = b2s[l];
#pragma unroll
    for (int k = 0; k < 32; ++k) {
        float h1k = h1[k];
        const float4* wr = (const float4*)&W2s[k * 32];
#pragma unroll
        for (int l4 = 0; l4 < 8; ++l4) {
            float4 w = wr[l4];
            h2[l4 * 4 + 0] += h1k * w.x;
            h2[l4 * 4 + 1] += h1k * w.y;
            h2[l4 * 4 + 2] += h1k * w.z;
            h2[l4 * 4 + 3] += h1k * w.w;
        }
    }

    float mu_acc = mu_b[0] + 1e-10f;
    float sg = sig_b[0];
#pragma unroll
    for (int l = 0; l < 32; ++l) {
        float h = h2[l];
        h = h > 0.f ? h : 0.01f * h;
        mu_acc += h * muWs[l];
        sg += h * sigWs[l];
    }
    float mu = softplusf(mu_acc);
    float sd = expf(fminf(fmaxf(sg, -20.f), 2.f));
    out[gid] = mu;
    out[NPAIR + gid] = sd;
}

// ---------------------------------------------------------------------------
// launch
// ---------------------------------------------------------------------------
extern "C" void kernel_launch(void* const* d_in, const int* in_sizes, int n_in,
                              void* d_out, int out_size, void* d_ws, size_t ws_size,
                              hipStream_t stream)
{
    const float* state  = (const float*)d_in[0];
    const float* conv_W = (const float*)d_in[1];
    const float* conv_b = (const float*)d_in[2];
    const float* lin1_W = (const float*)d_in[3];
    const float* lin1_b = (const float*)d_in[4];
    const float* lin2_W = (const float*)d_in[5];
    const float* lin2_b = (const float*)d_in[6];
    const float* mu_W   = (const float*)d_in[7];
    const float* mu_b   = (const float*)d_in[8];
    const float* sig_W  = (const float*)d_in[9];
    const float* sig_b  = (const float*)d_in[10];
    const int*   eidx   = (const int*)d_in[11];
    const int* e_src = eidx;
    const int* e_dst = eidx + NEDGE;

    float* out = (float*)d_out;

    // workspace layout (floats)
    float* ws = (float*)d_ws;
    float* xw   = ws;                               // N*128  (becomes x in-place)
    float* agg  = xw + (size_t)NNODE * 128;         // N*128
    float* uvb  = agg + (size_t)NNODE * 128;        // N*64
    float* dinv = uvb + (size_t)NNODE * 64;         // N
    int*   deg  = (int*)(dinv + NNODE);             // N
    float* Wp   = (float*)(deg + NNODE);            // 128*64

    // zero accumulators (ws is poisoned and not re-poisoned between replays)
    hipMemsetAsync(agg, 0, (size_t)NNODE * 128 * sizeof(float), stream);
    hipMemsetAsync(deg, 0, (size_t)NNODE * sizeof(int), stream);

    // pack W1
    pack_w1<<<32, 256, 0, stream>>>(lin1_W, Wp);

    // xw = state @ conv_W
    gemm_k128<<<dim3(NNODE / 64, 2), 256, 0, stream>>>(state, conv_W, xw, 128);

    // degree + dinv
    deg_count<<<NEDGE / 256, 256, 0, stream>>>(e_dst, deg);
    make_dinv<<<(NNODE + 255) / 256, 256, 0, stream>>>(deg, dinv);

    // scatter aggregation
    scatter_edges<<<(NEDGE * 32) / 256, 256, 0, stream>>>(e_src, e_dst, dinv, xw, agg);

    // x = relu(agg + xw*dinv^2 + b) + state   (in-place into xw)
    build_x<<<(NNODE * 32) / 256, 256, 0, stream>>>(xw, agg, dinv, conv_b, state);

    // uv = x @ [W1_top | W1_bot]
    gemm_k128<<<dim3(NNODE / 64, 1), 256, 0, stream>>>(xw, Wp, uvb, 64);

    // pairs -> output
    pairs_kernel<<<NPAIR / 256, 256, 0, stream>>>(
        uvb, lin2_W, lin1_b, lin2_b, mu_W, mu_b, sig_W, sig_b, out);
}

// Round 2
// 159.878 us; speedup vs baseline: 4.8897x; 4.8897x over previous
//
#include <hip/hip_runtime.h>
#include <hip/hip_bf16.h>
#include <math.h>

// Problem constants
#define NB    2048          // B
#define ACT   14
#define NC    128           // C
#define NH    32            // H
#define NNODE (NB*ACT)      // 28672
#define NEDGE (NB*ACT*ACT)  // 401408
#define NPAIR (NB*ACT*ACT)  // 401408 output rows (b, 196)

// ---------------------------------------------------------------------------
// tiled fp32 GEMM, A [nrows x 128] @ W [128 x ncols] -> C [nrows x ncols]
// 64x64 tile, 256 threads, 4x4 register blocking, XOR-swizzled A tile in LDS.
// Optional per-row output scale (rowscale != nullptr -> C[r,:] *= rowscale[r]).
// ---------------------------------------------------------------------------
__global__ __launch_bounds__(256) void gemm_k128(
    const float* __restrict__ A, const float* __restrict__ W,
    float* __restrict__ C, int ncols, const float* __restrict__ rowscale)
{
    __shared__ float As[64 * 128];   // 32 KB
    __shared__ float Ws[128 * 64];   // 32 KB
    const int tid  = threadIdx.x;
    const int row0 = blockIdx.x * 64;
    const int col0 = blockIdx.y * 64;

    {
        const float4* Ag = (const float4*)(A + (size_t)row0 * 128);
#pragma unroll
        for (int it = 0; it < 8; ++it) {
            int idx = tid + it * 256;          // float4 index in tile
            int r = idx >> 5;
            int c = (idx & 31) << 2;           // float col, multiple of 4
            int cs = c ^ (((r >> 2) & 3) << 2);
            *((float4*)&As[r * 128 + cs]) = Ag[r * 32 + (c >> 2)];
        }
#pragma unroll
        for (int it = 0; it < 8; ++it) {
            int idx = tid + it * 256;
            int k = idx >> 4;
            int c = (idx & 15) << 2;
            *((float4*)&Ws[k * 64 + c]) =
                *((const float4*)&W[(size_t)k * ncols + col0 + c]);
        }
    }
    __syncthreads();

    const int tx = tid & 15;       // col group
    const int ty = tid >> 4;       // row group
    const int ri0 = ty * 4;

    float acc[4][4] = {};
    for (int k = 0; k < 128; k += 4) {
        float a_s[4][4];
        float w_s[4][4];
#pragma unroll
        for (int i = 0; i < 4; ++i) {
            int r = ri0 + i;
            *((float4*)&a_s[i][0]) =
                *((const float4*)&As[r * 128 + (k ^ (((r >> 2) & 3) << 2))]);
        }
#pragma unroll
        for (int kk = 0; kk < 4; ++kk) {
            *((float4*)&w_s[kk][0]) =
                *((const float4*)&Ws[(k + kk) * 64 + tx * 4]);
        }
#pragma unroll
        for (int kk = 0; kk < 4; ++kk)
#pragma unroll
            for (int i = 0; i < 4; ++i)
#pragma unroll
                for (int j = 0; j < 4; ++j)
                    acc[i][j] += a_s[i][kk] * w_s[kk][j];
    }

#pragma unroll
    for (int i = 0; i < 4; ++i) {
        float s = rowscale ? rowscale[row0 + ri0 + i] : 1.0f;
        float4 v = make_float4(acc[i][0] * s, acc[i][1] * s,
                               acc[i][2] * s, acc[i][3] * s);
        *((float4*)&C[(size_t)(row0 + ri0 + i) * ncols + col0 + tx * 4]) = v;
    }
}

// ---------------------------------------------------------------------------
// pack W1 [256x32] -> Wp [128x64]  (cols 0..31 = W1[k], cols 32..63 = W1[128+k])
// ---------------------------------------------------------------------------
__global__ void pack_w1(const float* __restrict__ W1, float* __restrict__ Wp)
{
    int idx = blockIdx.x * blockDim.x + threadIdx.x;   // 0..8191
    if (idx >= 128 * 64) return;
    int k = idx >> 6, c = idx & 63;
    Wp[idx] = (c < 32) ? W1[k * 32 + c] : W1[(128 + k) * 32 + (c - 32)];
}

// ---------------------------------------------------------------------------
// degree histogram (int atomics)
// ---------------------------------------------------------------------------
__global__ void deg_count(const int* __restrict__ dst, int* __restrict__ deg)
{
    int e = blockIdx.x * blockDim.x + threadIdx.x;
    if (e < NEDGE) atomicAdd(&deg[dst[e]], 1);
}

// ---------------------------------------------------------------------------
// single-block exclusive scan of deg -> cursor (start offsets); also dinv.
// 28672 = 1024 threads x 28 elements each.
// ---------------------------------------------------------------------------
__global__ __launch_bounds__(1024) void scan_dinv(
    const int* __restrict__ deg, int* __restrict__ cursor,
    float* __restrict__ dinv)
{
    __shared__ int part[1024];
    const int t = threadIdx.x;
    const int base = t * 28;
    int local[28];
    int s = 0;
#pragma unroll
    for (int i = 0; i < 28; ++i) { local[i] = s; s += deg[base + i]; }
    part[t] = s;
    __syncthreads();
    int own = s;
    for (int off = 1; off < 1024; off <<= 1) {
        int tmp = (t >= off) ? part[t - off] : 0;
        __syncthreads();
        part[t] += tmp;
        __syncthreads();
    }
    int prefix = part[t] - own;   // exclusive prefix of this thread's chunk
#pragma unroll
    for (int i = 0; i < 28; ++i) {
        cursor[base + i] = prefix + local[i];
        dinv[base + i] = rsqrtf((float)deg[base + i] + 1.0f);
    }
}

// ---------------------------------------------------------------------------
// CSR fill: csr_src[pos] = src[e], pos = cursor[dst[e]]++  (int atomics)
// After this kernel cursor[d] == end offset of node d.
// ---------------------------------------------------------------------------
__global__ void csr_fill(const int* __restrict__ src, const int* __restrict__ dst,
                         int* __restrict__ cursor, int* __restrict__ csr_src)
{
    int e = blockIdx.x * blockDim.x + threadIdx.x;
    if (e < NEDGE) {
        int pos = atomicAdd(&cursor[dst[e]], 1);
        csr_src[pos] = src[e];
    }
}

// ---------------------------------------------------------------------------
// gather aggregation + GCN epilogue, fused:
//   x[d] = relu(dinv[d] * (y[d] + sum_{e->d} y[src]) + bias) + state[d]
// One 32-lane group per node; lane q owns channels [4q, 4q+4).
// ---------------------------------------------------------------------------
__global__ __launch_bounds__(256) void gather_agg(
    const int* __restrict__ csr_src, const int* __restrict__ cursor,
    const int* __restrict__ deg, const float* __restrict__ y,
    const float* __restrict__ dinv, const float* __restrict__ bias,
    const float* __restrict__ state, float* __restrict__ xout)
{
    const int lane = threadIdx.x & 31;
    const int d = (blockIdx.x * 256 + threadIdx.x) >> 5;   // node id
    if (d >= NNODE) return;

    const int cnt = deg[d];
    const int end = cursor[d];
    const int start = end - cnt;

    float4 acc = ((const float4*)(y + (size_t)d * NC))[lane];  // self loop
    for (int base = 0; base < cnt; base += 32) {
        int rem = cnt - base;
        int m = rem < 32 ? rem : 32;
        int sv = (lane < m) ? csr_src[start + base + lane] : 0;
        for (int j = 0; j < m; ++j) {
            int s = __shfl(sv, j, 32);
            float4 v = ((const float4*)(y + (size_t)s * NC))[lane];
            acc.x += v.x; acc.y += v.y; acc.z += v.z; acc.w += v.w;
        }
    }

    const float dv = dinv[d];
    float4 b  = ((const float4*)bias)[lane];
    float4 st = ((const float4*)(state + (size_t)d * NC))[lane];
    float4 r;
    r.x = fmaxf(acc.x * dv + b.x, 0.f) + st.x;
    r.y = fmaxf(acc.y * dv + b.y, 0.f) + st.y;
    r.z = fmaxf(acc.z * dv + b.z, 0.f) + st.z;
    r.w = fmaxf(acc.w * dv + b.w, 0.f) + st.w;
    ((float4*)(xout + (size_t)d * NC))[lane] = r;
}

// ---------------------------------------------------------------------------
// pairs kernel (unchanged)
// ---------------------------------------------------------------------------
__device__ __forceinline__ float softplusf(float z)
{
    return z > 0.f ? z + log1pf(expf(-z)) : log1pf(expf(z));
}

__global__ __launch_bounds__(256) void pairs_kernel(
    const float* __restrict__ uv, const float* __restrict__ W2,
    const float* __restrict__ b1, const float* __restrict__ b2,
    const float* __restrict__ muW, const float* __restrict__ mu_b,
    const float* __restrict__ sigW, const float* __restrict__ sig_b,
    float* __restrict__ out)
{
    __shared__ float W2s[1024];
    __shared__ float b1s[32], b2s[32], muWs[32], sigWs[32];
    const int tid = threadIdx.x;
    for (int i = tid; i < 1024; i += 256) W2s[i] = W2[i];
    if (tid < 32) {
        b1s[tid] = b1[tid];
        b2s[tid] = b2[tid];
        muWs[tid] = muW[tid];
        sigWs[tid] = sigW[tid];
    }
    __syncthreads();

    int gid = blockIdx.x * 256 + tid;          // 0 .. NPAIR-1
    int b = gid / 196;
    int p = gid - b * 196;
    int i = p / 14;
    int j = p - i * 14;

    const float* up = uv + (size_t)(b * ACT + i) * 64;
    const float* vp = uv + (size_t)(b * ACT + j) * 64 + 32;

    float h1[32];
#pragma unroll
    for (int k4 = 0; k4 < 8; ++k4) {
        float4 uu = ((const float4*)up)[k4];
        float4 vv = ((const float4*)vp)[k4];
        float z0 = uu.x + vv.x + b1s[k4 * 4 + 0];
        float z1 = uu.y + vv.y + b1s[k4 * 4 + 1];
        float z2 = uu.z + vv.z + b1s[k4 * 4 + 2];
        float z3 = uu.w + vv.w + b1s[k4 * 4 + 3];
        h1[k4 * 4 + 0] = z0 > 0.f ? z0 : 0.01f * z0;
        h1[k4 * 4 + 1] = z1 > 0.f ? z1 : 0.01f * z1;
        h1[k4 * 4 + 2] = z2 > 0.f ? z2 : 0.01f * z2;
        h1[k4 * 4 + 3] = z3 > 0.f ? z3 : 0.01f * z3;
    }

    float h2[32];
#pragma unroll
    for (int l = 0; l < 32; ++l) h2[l] = b2s[l];
#pragma unroll
    for (int k = 0; k < 32; ++k) {
        float h1k = h1[k];
        const float4* wr = (const float4*)&W2s[k * 32];
#pragma unroll
        for (int l4 = 0; l4 < 8; ++l4) {
            float4 w = wr[l4];
            h2[l4 * 4 + 0] += h1k * w.x;
            h2[l4 * 4 + 1] += h1k * w.y;
            h2[l4 * 4 + 2] += h1k * w.z;
            h2[l4 * 4 + 3] += h1k * w.w;
        }
    }

    float mu_acc = mu_b[0] + 1e-10f;
    float sg = sig_b[0];
#pragma unroll
    for (int l = 0; l < 32; ++l) {
        float h = h2[l];
        h = h > 0.f ? h : 0.01f * h;
        mu_acc += h * muWs[l];
        sg += h * sigWs[l];
    }
    float mu = softplusf(mu_acc);
    float sd = expf(fminf(fmaxf(sg, -20.f), 2.f));
    out[gid] = mu;
    out[NPAIR + gid] = sd;
}

// ---------------------------------------------------------------------------
// launch
// ---------------------------------------------------------------------------
extern "C" void kernel_launch(void* const* d_in, const int* in_sizes, int n_in,
                              void* d_out, int out_size, void* d_ws, size_t ws_size,
                              hipStream_t stream)
{
    const float* state  = (const float*)d_in[0];
    const float* conv_W = (const float*)d_in[1];
    const float* conv_b = (const float*)d_in[2];
    const float* lin1_W = (const float*)d_in[3];
    const float* lin1_b = (const float*)d_in[4];
    const float* lin2_W = (const float*)d_in[5];
    const float* lin2_b = (const float*)d_in[6];
    const float* mu_W   = (const float*)d_in[7];
    const float* mu_b   = (const float*)d_in[8];
    const float* sig_W  = (const float*)d_in[9];
    const float* sig_b  = (const float*)d_in[10];
    const int*   eidx   = (const int*)d_in[11];
    const int* e_src = eidx;
    const int* e_dst = eidx + NEDGE;

    float* out = (float*)d_out;

    // workspace layout (floats)
    float* ws = (float*)d_ws;
    float* y     = ws;                               // N*128 (xw*dinv; later reused for uv)
    float* x     = y + (size_t)NNODE * 128;          // N*128
    float* dinv  = x + (size_t)NNODE * 128;          // N
    int*   deg   = (int*)(dinv + NNODE);             // N
    int*   cursor= deg + NNODE;                      // N
    int*   csrs  = cursor + NNODE;                   // E
    float* Wp    = (float*)(csrs + NEDGE);           // 128*64
    float* uvb   = y;                                // reuse: uv [N x 64]

    // zero the degree histogram (ws is poisoned once, never re-poisoned)
    hipMemsetAsync(deg, 0, (size_t)NNODE * sizeof(int), stream);

    // CSR build
    deg_count<<<NEDGE / 256, 256, 0, stream>>>(e_dst, deg);
    scan_dinv<<<1, 1024, 0, stream>>>(deg, cursor, dinv);
    csr_fill<<<NEDGE / 256, 256, 0, stream>>>(e_src, e_dst, cursor, csrs);

    // pack W1
    pack_w1<<<32, 256, 0, stream>>>(lin1_W, Wp);

    // y = (state @ conv_W) * dinv[row]
    gemm_k128<<<dim3(NNODE / 64, 2), 256, 0, stream>>>(state, conv_W, y, 128, dinv);

    // x = relu(dinv*(y_self + sum y[src]) + b) + state
    gather_agg<<<(NNODE * 32) / 256, 256, 0, stream>>>(
        csrs, cursor, deg, y, dinv, conv_b, state, x);

    // uv = x @ [W1_top | W1_bot]   (overwrites y region)
    gemm_k128<<<dim3(NNODE / 64, 1), 256, 0, stream>>>(x, Wp, uvb, 64, nullptr);

    // pairs -> output
    pairs_kernel<<<NPAIR / 256, 256, 0, stream>>>(
        uvb, lin2_W, lin1_b, lin2_b, mu_W, mu_b, sig_W, sig_b, out);
}